// Round 10
// baseline (349.914 us; speedup 1.0000x reference)
//
#include <hip/hip_runtime.h>
#include <hip/hip_bf16.h>

#define Bc   2
#define Hc   64
#define Wc   64
#define Lc   4096
#define Cc   96
#define Ec   192
#define Nc   16
#define CATc 768
#define CHUNK 16
#define NCH  256
#define XJ   38
#define PF   8

// ---------------- scan-order closed forms (H=W=64) ----------------
__device__ __forceinline__ int inv_d0(int l) {           // bottom-up boustrophedon rows
    int i = l >> 6, j = l & 63;
    int k = 63 - i;
    int m = (k & 1) ? (63 - j) : j;
    return k * 64 + m;
}
__device__ __forceinline__ int inv_d1(int l) {           // left-right boustrophedon cols
    int i = l >> 6, j = l & 63;
    int m = (j & 1) ? (63 - i) : i;
    return j * 64 + m;
}
__device__ __forceinline__ int diag_off(int d) {
    return (d <= 63) ? (d * (d + 1) / 2) : (4096 - (127 - d) * (128 - d) / 2);
}
__device__ __forceinline__ int inv_d2(int l) {           // diagonals
    int i = l >> 6, j = l & 63;
    int d = i + j;
    int st = d > 63 ? d - 63 : 0;
    return diag_off(d) + (i - st);
}
__device__ __forceinline__ int inv_d3(int l) {           // anti-diagonals
    int i = l >> 6, jj = l & 63;
    int j = 63 - jj;
    int d = i + j;
    int st = d > 63 ? d - 63 : 0;
    return diag_off(d) + (i - st);
}

// setup: 0..15 ord; 16..87 wout^T; 88..375 fw^T; 376..404 xw^T;
//        405..548 ipw^T; 549..620 clw^T
__global__ __launch_bounds__(256) void setup_kernel(
    int* __restrict__ ord, const float* __restrict__ wout,
    float* __restrict__ woutT, const float* __restrict__ fw,
    float* __restrict__ fwT, const float* __restrict__ xw,
    float* __restrict__ xwT, const float* __restrict__ ipw,
    float* __restrict__ ipwT, const float* __restrict__ clw,
    float* __restrict__ clwT) {
    if (blockIdx.x < 16) {
        int l = blockIdx.x * 256 + threadIdx.x;
        ord[0 * Lc + inv_d0(l)] = l;
        ord[1 * Lc + inv_d1(l)] = l;
        ord[2 * Lc + inv_d2(l)] = l;
        ord[3 * Lc + inv_d3(l)] = l;
    } else if (blockIdx.x < 88) {
        int idx = (blockIdx.x - 16) * 256 + threadIdx.x;
        if (idx < Ec * Cc) {
            int k = idx / Cc, o = idx % Cc;
            woutT[idx] = wout[o * Ec + k];
        }
    } else if (blockIdx.x < 376) {
        int idx = (blockIdx.x - 88) * 256 + threadIdx.x;   // 288 blocks = 73728
        int k = idx / Cc, o = idx % Cc;                    // fwT[k][o] = fw[o][k]
        fwT[idx] = fw[o * CATc + k];
    } else if (blockIdx.x < 405) {
        int idx = (blockIdx.x - 376) * 256 + threadIdx.x;  // 29 blocks, 7296 elems
        if (idx < Ec * XJ) {
            int c = idx / XJ, j = idx % XJ;                // xwT[c][j] = xw[j][c]
            xwT[idx] = xw[j * Ec + c];
        }
    } else if (blockIdx.x < 549) {
        int idx = (blockIdx.x - 405) * 256 + threadIdx.x;  // 144 blocks = 36864
        int c = idx / (2 * Ec), o = idx % (2 * Ec);        // ipwT[c][o] = ipw[o][c]
        ipwT[idx] = ipw[o * Cc + c];
    } else {
        int idx = (blockIdx.x - 549) * 256 + threadIdx.x;  // 72 blocks = 18432
        int c = idx / Ec, o = idx % Ec;                    // clwT[c][o] = clw[o][c]
        clwT[idx] = clw[o * Cc + c];
    }
}

// ---------------- directional convs + SiLU -> cat [B,768,L] ----------------
__global__ __launch_bounds__(256) void conv_kernel(
    const float* __restrict__ x, const float* __restrict__ wh,
    const float* __restrict__ wv, const float* __restrict__ wd1,
    const float* __restrict__ wd2, float* __restrict__ cat) {
    int tile = blockIdx.x, ic = blockIdx.y, b = blockIdx.z;
    int th0 = (tile >> 2) * 16, tw0 = (tile & 3) * 16;
    __shared__ float S[22][24];
    int tid = threadIdx.x;
    for (int idx = tid; idx < 22 * 22; idx += 256) {
        int r = idx / 22, c = idx % 22;
        int gh = th0 + r - 3, gw = tw0 + c - 3;
        float v = 0.f;
        if (gh >= 0 && gh < 64 && gw >= 0 && gw < 64)
            v = x[((size_t)b * Lc + gh * 64 + gw) * Cc + ic];
        S[r][c] = v;
    }
    __syncthreads();
    int ti = tid >> 4, tj = tid & 15;
    int pix = (th0 + ti) * 64 + (tw0 + tj);
    for (int s = 0; s < 2; s++) {
        int o = 2 * ic + s;
        float ah = 0.f, av = 0.f, a1 = 0.f, a2 = 0.f;
#pragma unroll
        for (int t = 0; t < 7; t++) {
            ah += S[ti + 3][tj + t] * wh[o * 7 + t];
            av += S[ti + t][tj + 3] * wv[o * 7 + t];
        }
#pragma unroll
        for (int r = 0; r < 7; r++)
#pragma unroll
            for (int c2 = 0; c2 < 7; c2++) {
                float sv = S[ti + r][tj + c2];
                a1 += sv * wd1[o * 49 + r * 7 + c2];
                a2 += sv * wd2[o * 49 + r * 7 + c2];
            }
        cat[((size_t)b * CATc + 0 * Ec + o) * Lc + pix] = ah / (1.f + __expf(-ah));
        cat[((size_t)b * CATc + 1 * Ec + o) * Lc + pix] = av / (1.f + __expf(-av));
        cat[((size_t)b * CATc + 2 * Ec + o) * Lc + pix] = a1 / (1.f + __expf(-a1));
        cat[((size_t)b * CATc + 3 * Ec + o) * Lc + pix] = a2 / (1.f + __expf(-a2));
    }
}

// ---------------- fuse v4: thread-owns-l, FULL 96-o accumulation, cat read ONCE ----------------
// R9: the two o-half passes each streamed the 25 MB cat through L3. 96 acc regs
// (statically indexed, fully unrolled j-loop) fit the register file; 96 FMA per
// load = 192 cyc ILP per ~500 cyc L3 load, latency hidden by unroll-4 without TLP.
__global__ __launch_bounds__(256) void fuse_part(
    const float* __restrict__ cat, const float* __restrict__ fwT,
    float* __restrict__ pxconv) {
    int l  = blockIdx.x * 256 + threadIdx.x;   // 0..4095 within batch
    int kc = blockIdx.y;                        // 8 chunks of 96 k
    int b  = blockIdx.z;
    float acc[96];
#pragma unroll
    for (int j = 0; j < 96; j++) acc[j] = 0.f;
    const float* csrc = cat + ((size_t)b * CATc + kc * 96) * Lc + l;
    const float* wsrc = fwT + (size_t)(kc * 96) * Cc;
#pragma unroll 4
    for (int k = 0; k < 96; k++) {
        float v = csrc[(size_t)k * Lc];
        const float* wr = wsrc + (size_t)k * Cc;   // uniform -> s_load
#pragma unroll
        for (int j = 0; j < 96; j++) acc[j] += v * wr[j];
    }
    float* dst = pxconv + (((size_t)kc * Bc + b) * Cc) * Lc + l;
#pragma unroll
    for (int j = 0; j < 96; j++) dst[(size_t)j * Lc] = acc[j];
}

__global__ __launch_bounds__(256) void fuse_reduce(
    const float* __restrict__ pxconv, float* __restrict__ xconv) {
    size_t idx = ((size_t)blockIdx.x * 256 + threadIdx.x) * 4;   // float4 over Bc*Cc*Lc
    const size_t stride = (size_t)Bc * Cc * Lc;
    float4 s = *(const float4*)(pxconv + idx);
#pragma unroll
    for (int k = 1; k < 8; k++) {
        float4 v = *(const float4*)(pxconv + idx + (size_t)k * stride);
        s.x += v.x; s.y += v.y; s.z += v.z; s.w += v.w;
    }
    *(float4*)(xconv + idx) = s;
}

// ---------------- in_proj v3: 48-o slices, scalar ipwT ----------------
__global__ __launch_bounds__(256) void inproj_kernel(
    const float* __restrict__ xconv, const float* __restrict__ ipwT,
    float* __restrict__ xp, float* __restrict__ zp, float* __restrict__ xpT) {
    int l = blockIdx.x * 256 + threadIdx.x;
    int o0 = blockIdx.y * 48;              // 8 groups: 0..3 -> xp, 4..7 -> zp
    int b = blockIdx.z;
    float acc[48];
#pragma unroll
    for (int j = 0; j < 48; j++) acc[j] = 0.f;
    const float* csrc = xconv + (size_t)b * Cc * Lc + l;
    const float* wsrc = ipwT + o0;
#pragma unroll 4
    for (int c = 0; c < Cc; c++) {
        float v = csrc[(size_t)c * Lc];
        const float* wr = wsrc + c * (2 * Ec);   // uniform -> s_load
#pragma unroll
        for (int j = 0; j < 48; j++) acc[j] += v * wr[j];
    }
    if (o0 < Ec) {
        float* xr = xp + ((size_t)b * Lc + l) * Ec + o0;
#pragma unroll
        for (int j = 0; j < 48; j++) xr[j] = acc[j];
        float* xt = xpT + (size_t)o0 * (Bc * Lc) + b * Lc + l;
#pragma unroll
        for (int j = 0; j < 48; j++) xt[(size_t)j * (Bc * Lc)] = acc[j];  // coalesced
    } else {
        float* zr = zp + ((size_t)b * Lc + l) * Ec + (o0 - Ec);
#pragma unroll
        for (int j = 0; j < 48; j++) zr[j] = acc[j];
    }
}

// ---------------- xdbl GEMM v2: thread-owns-row, scalar xwT, split-K 8 ----------------
// pxd layout [kc][j][r], r = b*Lc + l flat (8192)
__global__ __launch_bounds__(256) void xdbl_gemm(
    const float* __restrict__ xpT, const float* __restrict__ xwT,
    float* __restrict__ pxd) {
    int r  = blockIdx.x * 256 + threadIdx.x;   // 0..8191
    int kc = blockIdx.y;                        // 8 chunks of 24 k
    float acc[XJ];
#pragma unroll
    for (int j = 0; j < XJ; j++) acc[j] = 0.f;
    const float* src = xpT + (size_t)(kc * 24) * (Bc * Lc) + r;
    const float* w   = xwT + kc * 24 * XJ;
#pragma unroll 4
    for (int k = 0; k < 24; k++) {
        float v = src[(size_t)k * (Bc * Lc)];
        const float* wr = w + k * XJ;           // uniform -> s_load
#pragma unroll
        for (int j = 0; j < XJ; j++) acc[j] += v * wr[j];
    }
    float* dst = pxd + (size_t)kc * XJ * (Bc * Lc) + r;
#pragma unroll
    for (int j = 0; j < XJ; j++) dst[(size_t)j * (Bc * Lc)] = acc[j];
}

// reduce 8 partials -> dt6R [6][8192], BstT/CstT [b][n][l]
__global__ __launch_bounds__(256) void xdbl_reduce(
    const float* __restrict__ pxd, float* __restrict__ dt6R,
    float* __restrict__ BstT, float* __restrict__ CstT) {
    int idx = blockIdx.x * 256 + threadIdx.x;   // j*8192 + r, exactly 38*8192
    float s = 0.f;
#pragma unroll
    for (int kc = 0; kc < 8; kc++) s += pxd[(size_t)kc * XJ * (Bc * Lc) + idx];
    int j = idx >> 13, r = idx & (Bc * Lc - 1);
    int b = r >> 12, l = r & (Lc - 1);
    if (j < 6)       dt6R[j * (Bc * Lc) + r] = s;
    else if (j < 22) BstT[((size_t)b * Nc + (j - 6)) * Lc + l] = s;
    else             CstT[((size_t)b * Nc + (j - 22)) * Lc + l] = s;
}

// delta[row][e] = softplus(dt6R[.][row] @ dtw^T + 2*dtb)   (coalesced writes)
__global__ __launch_bounds__(192) void delta_kernel(
    const float* __restrict__ dt6R, const float* __restrict__ dtw,
    const float* __restrict__ dtb, float* __restrict__ delta) {
    int r = blockIdx.x;          // 0..8191 flat row
    int e = threadIdx.x;         // 0..191
    const float* w = dtw + e * 6;
    float s = 2.f * dtb[e];
#pragma unroll
    for (int rr = 0; rr < 6; rr++) s += dt6R[rr * (Bc * Lc) + r] * w[rr];
    delta[(size_t)r * Ec + e] = (s > 20.f) ? s : __logf(1.f + __expf(s));
}

// ============ chunked selective scan, d-FUSED, PREFETCHED ============

__global__ __launch_bounds__(192, 2) void scan_part1(
    const float* __restrict__ xp, const int* __restrict__ ord,
    const float* __restrict__ delta, const float* __restrict__ BstT,
    const float* __restrict__ A_log, const float* __restrict__ dirB,
    float* __restrict__ hend, float* __restrict__ Pend) {
    int chunk = blockIdx.x, b = blockIdx.y;
    int e = threadIdx.x;                 // 0..191
    int l0 = chunk * CHUNK;
    __shared__ int lord[4][CHUNK];
    __shared__ float4 Bs[CHUNK][Nc];     // (B[n][l] + dirB[d][n]) packed over d
    if (threadIdx.x < 64) {
        int d = threadIdx.x >> 4, t = threadIdx.x & 15;
        lord[d][t] = ord[d * Lc + l0 + t];
    }
    {
        const float* Bb = BstT + (size_t)b * Nc * Lc;
        for (int idx = threadIdx.x; idx < CHUNK * Nc; idx += 192) {
            int n = idx >> 4, t = idx & 15;
            float Bn = Bb[(size_t)n * Lc + l0 + t];
            Bs[t][n] = make_float4(Bn + dirB[0 * Nc + n], Bn + dirB[1 * Nc + n],
                                   Bn + dirB[2 * Nc + n], Bn + dirB[3 * Nc + n]);
        }
    }
    __syncthreads();
    const float* dl  = delta + (size_t)b * Lc * Ec + e;
    const float* xpb = xp + (size_t)b * Lc * Ec + e;
    float de[CHUNK], u0[CHUNK], u1[CHUNK], u2[CHUNK], u3[CHUNK];
#pragma unroll
    for (int t = 0; t < CHUNK; t++) de[t] = dl[(size_t)(l0 + t) * Ec];
#pragma unroll
    for (int t = 0; t < CHUNK; t++) {
        u0[t] = xpb[(size_t)lord[0][t] * Ec];
        u1[t] = xpb[(size_t)lord[1][t] * Ec];
        u2[t] = xpb[(size_t)lord[2][t] * Ec];
        u3[t] = xpb[(size_t)lord[3][t] * Ec];
    }
    float Aen[Nc], P[Nc], h0[Nc], h1[Nc], h2[Nc], h3[Nc];
#pragma unroll
    for (int n = 0; n < Nc; n++) {
        Aen[n] = -__expf(A_log[e * Nc + n]);
        P[n] = 1.f; h0[n] = 0.f; h1[n] = 0.f; h2[n] = 0.f; h3[n] = 0.f;
    }
#pragma unroll
    for (int t = 0; t < CHUNK; t++) {
        float du0 = de[t] * u0[t], du1 = de[t] * u1[t];
        float du2 = de[t] * u2[t], du3 = de[t] * u3[t];
#pragma unroll
        for (int n = 0; n < Nc; n++) {
            float dA = __expf(de[t] * Aen[n]);             // ONE exp for 4 dirs
            float4 B4 = Bs[t][n];                          // LDS broadcast
            P[n] *= dA;
            h0[n] = dA * h0[n] + du0 * B4.x;
            h1[n] = dA * h1[n] + du1 * B4.y;
            h2[n] = dA * h2[n] + du2 * B4.z;
            h3[n] = dA * h3[n] + du3 * B4.w;
        }
    }
    size_t cb = ((size_t)b * NCH + chunk) * 3072 + e;
    const size_t dstr = (size_t)Bc * NCH * 3072;
#pragma unroll
    for (int n = 0; n < Nc; n++) {
        hend[cb + 0 * dstr + n * Ec] = h0[n];
        hend[cb + 1 * dstr + n * Ec] = h1[n];
        hend[cb + 2 * dstr + n * Ec] = h2[n];
        hend[cb + 3 * dstr + n * Ec] = h3[n];
        Pend[cb + n * Ec] = P[n];
    }
}

// 384 blocks x 64 thr; 8-deep software pipeline.
__global__ __launch_bounds__(64) void scan_mid(
    float* __restrict__ hend, const float* __restrict__ Pend) {
    int blk = blockIdx.x;            // db*48 + sub
    int sub = blk % 48, db = blk / 48;
    int b = db & 1;
    int pair = sub * 64 + threadIdx.x;   // 0..3071 = (n,e) flat
    size_t base  = (size_t)db * NCH * 3072 + pair;
    size_t pbase = (size_t)b * NCH * 3072 + pair;
    float hbuf[PF], Pbuf[PF];
#pragma unroll
    for (int i = 0; i < PF; i++) {
        hbuf[i] = hend[base + (size_t)i * 3072];
        Pbuf[i] = Pend[pbase + (size_t)i * 3072];
    }
    float h = 0.f;
    for (int c = 0; c < NCH; c += PF) {
#pragma unroll
        for (int i = 0; i < PF; i++) {
            float hc = hbuf[i], P = Pbuf[i];
            int cn = c + i + PF;
            if (cn < NCH) {
                hbuf[i] = hend[base + (size_t)cn * 3072];
                Pbuf[i] = Pend[pbase + (size_t)cn * 3072];
            }
            hend[base + (size_t)(c + i) * 3072] = h;   // h_in for chunk c+i
            h = P * h + hc;
        }
    }
}

// scan_part2 v2: writes y directly at SPATIAL position (lord[d][t]) instead of
// scan position — the permutation is already in LDS; rows stay per-row coalesced
// and the scatter is a bijection (no races). final_kernel then reads all 4 dirs
// + zp + cl at the SAME row lp (one locality cluster, no inv_d math).
__global__ __launch_bounds__(192, 2) void scan_part2(
    const float* __restrict__ xp, const int* __restrict__ ord,
    const float* __restrict__ delta, const float* __restrict__ BstT,
    const float* __restrict__ CstT, const float* __restrict__ A_log,
    const float* __restrict__ Dp, const float* __restrict__ dirB,
    const float* __restrict__ hend, float* __restrict__ ydir) {
    int chunk = blockIdx.x, b = blockIdx.y;
    int e = threadIdx.x;                 // 0..191
    int l0 = chunk * CHUNK;
    __shared__ int lord[4][CHUNK];
    __shared__ float4 Bs[CHUNK][Nc];
    __shared__ float Cs[CHUNK][Nc];
    if (threadIdx.x < 64) {
        int d = threadIdx.x >> 4, t = threadIdx.x & 15;
        lord[d][t] = ord[d * Lc + l0 + t];
    }
    {
        const float* Bb = BstT + (size_t)b * Nc * Lc;
        const float* Cb = CstT + (size_t)b * Nc * Lc;
        for (int idx = threadIdx.x; idx < CHUNK * Nc; idx += 192) {
            int n = idx >> 4, t = idx & 15;
            float Bn = Bb[(size_t)n * Lc + l0 + t];
            Bs[t][n] = make_float4(Bn + dirB[0 * Nc + n], Bn + dirB[1 * Nc + n],
                                   Bn + dirB[2 * Nc + n], Bn + dirB[3 * Nc + n]);
            Cs[t][n] = Cb[(size_t)n * Lc + l0 + t];
        }
    }
    __syncthreads();
    const float* dl  = delta + (size_t)b * Lc * Ec + e;
    const float* xpb = xp + (size_t)b * Lc * Ec + e;
    float de[CHUNK], u0[CHUNK], u1[CHUNK], u2[CHUNK], u3[CHUNK];
#pragma unroll
    for (int t = 0; t < CHUNK; t++) de[t] = dl[(size_t)(l0 + t) * Ec];
#pragma unroll
    for (int t = 0; t < CHUNK; t++) {
        u0[t] = xpb[(size_t)lord[0][t] * Ec];
        u1[t] = xpb[(size_t)lord[1][t] * Ec];
        u2[t] = xpb[(size_t)lord[2][t] * Ec];
        u3[t] = xpb[(size_t)lord[3][t] * Ec];
    }
    float Aen[Nc], h0[Nc], h1[Nc], h2[Nc], h3[Nc];
    size_t cb = ((size_t)b * NCH + chunk) * 3072 + e;
    const size_t dstr = (size_t)Bc * NCH * 3072;
#pragma unroll
    for (int n = 0; n < Nc; n++) {
        Aen[n] = -__expf(A_log[e * Nc + n]);
        h0[n] = hend[cb + 0 * dstr + n * Ec];
        h1[n] = hend[cb + 1 * dstr + n * Ec];
        h2[n] = hend[cb + 2 * dstr + n * Ec];
        h3[n] = hend[cb + 3 * dstr + n * Ec];
    }
    float De = Dp[e];
    float* yo0 = ydir + ((size_t)(0 * Bc + b) * Lc) * Ec + e;
    float* yo1 = ydir + ((size_t)(1 * Bc + b) * Lc) * Ec + e;
    float* yo2 = ydir + ((size_t)(2 * Bc + b) * Lc) * Ec + e;
    float* yo3 = ydir + ((size_t)(3 * Bc + b) * Lc) * Ec + e;
#pragma unroll
    for (int t = 0; t < CHUNK; t++) {
        float du0 = de[t] * u0[t], du1 = de[t] * u1[t];
        float du2 = de[t] * u2[t], du3 = de[t] * u3[t];
        float a0 = De * u0[t], a1 = De * u1[t];
        float a2 = De * u2[t], a3 = De * u3[t];
#pragma unroll
        for (int n = 0; n < Nc; n++) {
            float dA = __expf(de[t] * Aen[n]);             // ONE exp for 4 dirs
            float4 B4 = Bs[t][n];
            float Cn = Cs[t][n];
            h0[n] = dA * h0[n] + du0 * B4.x;
            h1[n] = dA * h1[n] + du1 * B4.y;
            h2[n] = dA * h2[n] + du2 * B4.z;
            h3[n] = dA * h3[n] + du3 * B4.w;
            a0 += h0[n] * Cn; a1 += h1[n] * Cn;
            a2 += h2[n] * Cn; a3 += h3[n] * Cn;
        }
        yo0[(size_t)lord[0][t] * Ec] = a0;    // scatter to spatial order
        yo1[(size_t)lord[1][t] * Ec] = a1;
        yo2[(size_t)lord[2][t] * Ec] = a2;
        yo3[(size_t)lord[3][t] * Ec] = a3;
    }
}

// ---------------- local cluster v2: 256 threads/block ----------------
__global__ __launch_bounds__(256) void cluster_kernel(
    const float* __restrict__ xconv,
    const float* __restrict__ fwp, const float* __restrict__ fbp,
    const float* __restrict__ vwp, const float* __restrict__ vbp,
    const float* __restrict__ pwp, const float* __restrict__ pbp,
    const float* __restrict__ alphap, const float* __restrict__ betap,
    float* __restrict__ c96T) {
    int g = blockIdx.x;
    int b = g >> 6, Wg = (g >> 3) & 7, Hg = g & 7;
    int tid = threadIdx.x;
    int p = tid & 63, q = tid >> 6;
    int wi = p >> 3, hj = p & 7;
    int lsp = (Wg * 8 + wi) * 64 + (Hg * 8 + hj);
    __shared__ float fS[64][6], vS[64][6];
    __shared__ float fP[4][64][6], vP[4][64][6];
    __shared__ float cen[25][6], vc[25][6], cnorm[25];
    __shared__ float simb[64];
    __shared__ int kb[64];
    __shared__ float aggP[4][25][8];     // [q][k][0..5]=sum s*v, [6]=sum_s
    __shared__ float agg[25][6];
    // phase A: input proj, 12 c's per (p,q)
    float fr[6], vr[6];
#pragma unroll
    for (int oc = 0; oc < 6; oc++) { fr[oc] = 0.f; vr[oc] = 0.f; }
    for (int c = q * 12; c < q * 12 + 12; c++) {
        float v1 = xconv[((size_t)b * Cc + c) * Lc + lsp];
        float v2 = xconv[((size_t)b * Cc + 48 + c) * Lc + lsp];
#pragma unroll
        for (int oc = 0; oc < 6; oc++) {
            fr[oc] += v1 * fwp[oc * 48 + c];
            vr[oc] += v2 * vwp[oc * 48 + c];
        }
    }
#pragma unroll
    for (int oc = 0; oc < 6; oc++) { fP[q][p][oc] = fr[oc]; vP[q][p][oc] = vr[oc]; }
    __syncthreads();
    if (q == 0) {
#pragma unroll
        for (int oc = 0; oc < 6; oc++) {
            fS[p][oc] = fbp[oc] + fP[0][p][oc] + fP[1][p][oc] + fP[2][p][oc] + fP[3][p][oc];
            vS[p][oc] = vbp[oc] + vP[0][p][oc] + vP[1][p][oc] + vP[2][p][oc] + vP[3][p][oc];
        }
    }
    __syncthreads();
    // phase B: adaptive-pool bins for 8->5 (150 items over 256 threads)
    const int bs[5] = {0, 1, 3, 4, 6}, be[5] = {2, 4, 5, 7, 8};
    if (tid < 150) {
        int k = tid / 6, oc = tid % 6;
        int ki = k / 5, kj = k % 5;
        float sf = 0.f, sv = 0.f;
        int cnt = 0;
        for (int ii = bs[ki]; ii < be[ki]; ii++)
            for (int jj = bs[kj]; jj < be[kj]; jj++) {
                sf += fS[ii * 8 + jj][oc];
                sv += vS[ii * 8 + jj][oc];
                cnt++;
            }
        cen[k][oc] = sf / cnt;
        vc[k][oc] = sv / cnt;
    }
    __syncthreads();
    if (tid < 25) {
        float s = 0.f;
#pragma unroll
        for (int oc = 0; oc < 6; oc++) s += cen[tid][oc] * cen[tid][oc];
        cnorm[tid] = 1.f / fmaxf(sqrtf(s), 1e-12f);
    }
    __syncthreads();
    // phase C: per-p argmax over 25 centers (first-occurrence semantics)
    if (q == 0) {
        float f2[6];
#pragma unroll
        for (int oc = 0; oc < 6; oc++) f2[oc] = fS[p][oc];
        float fn2 = 0.f;
#pragma unroll
        for (int oc = 0; oc < 6; oc++) fn2 += f2[oc] * f2[oc];
        float finv = 1.f / fmaxf(sqrtf(fn2), 1e-12f);
        float alpha = alphap[0], beta = betap[0];
        float best = -1.f;
        int bestk = 0;
        for (int k = 0; k < 25; k++) {
            float dot = 0.f;
#pragma unroll
            for (int oc = 0; oc < 6; oc++) dot += cen[k][oc] * f2[oc];
            float xv = beta + alpha * dot * cnorm[k] * finv;
            float s = 1.f / (1.f + __expf(-xv));
            if (s > best) { best = s; bestk = k; }
        }
        simb[p] = best;
        kb[p] = bestk;
    }
    __syncthreads();
    // phase D: agg — each (p<25, q) scans 16 of the 64 positions
    if (p < 25) {
        float sum_s = 0.f;
        float av[6];
#pragma unroll
        for (int oc = 0; oc < 6; oc++) av[oc] = 0.f;
        for (int qq = q * 16; qq < q * 16 + 16; qq++) {
            if (kb[qq] == p) {
                float s = simb[qq];
                sum_s += s;
#pragma unroll
                for (int oc = 0; oc < 6; oc++) av[oc] += s * vS[qq][oc];
            }
        }
#pragma unroll
        for (int oc = 0; oc < 6; oc++) aggP[q][p][oc] = av[oc];
        aggP[q][p][6] = sum_s;
    }
    __syncthreads();
    if (q == 0 && p < 25) {
        float sum_s = aggP[0][p][6] + aggP[1][p][6] + aggP[2][p][6] + aggP[3][p][6];
        float invd = 1.f / (sum_s + 1.f);
#pragma unroll
        for (int oc = 0; oc < 6; oc++)
            agg[p][oc] = (vc[p][oc] + aggP[0][p][oc] + aggP[1][p][oc] +
                          aggP[2][p][oc] + aggP[3][p][oc]) * invd;
    }
    __syncthreads();
    // phase E: output proj, 24 oo's per (p,q)
    float outp[6];
    {
        int k = kb[p];
        float s = simb[p];
#pragma unroll
        for (int oc = 0; oc < 6; oc++) outp[oc] = agg[k][oc] * s;
    }
    float* ocol = c96T + (size_t)b * Cc * Lc + lsp;
    for (int oo = q * 24; oo < q * 24 + 24; oo++) {
        float s = pbp[oo];
#pragma unroll
        for (int oc = 0; oc < 6; oc++) s += outp[oc] * pwp[oo * 6 + oc];
        ocol[(size_t)oo * Lc] = s;           // c96T[b][oo][lsp]
    }
}

// ---------------- cluster projection v2: c96T input, scalar clwT, 24-o slices ----------------
__global__ __launch_bounds__(256) void clproj_kernel(
    const float* __restrict__ c96T, const float* __restrict__ clwT,
    const float* __restrict__ bias, float* __restrict__ cl) {
    int l = blockIdx.x * 256 + threadIdx.x;
    int o0 = blockIdx.y * 24;              // 8 groups
    int b = blockIdx.z;
    float acc[24];
#pragma unroll
    for (int j = 0; j < 24; j++) acc[j] = bias[o0 + j];
    const float* csrc = c96T + (size_t)b * Cc * Lc + l;
    const float* wsrc = clwT + o0;
#pragma unroll 4
    for (int c = 0; c < Cc; c++) {
        float v = csrc[(size_t)c * Lc];
        const float* wr = wsrc + c * Ec;       // uniform -> s_load
#pragma unroll
        for (int j = 0; j < 24; j++) acc[j] += v * wr[j];
    }
    float* cr = cl + ((size_t)b * Lc + l) * Ec + o0;
#pragma unroll
    for (int j = 0; j < 24; j++) cr[j] = acc[j];
}

// ---------------- y sum (now all at row lp) + 3x LayerNorm + branch softmax + out_proj ----------------
__global__ __launch_bounds__(256) void final_kernel(
    const float* __restrict__ ydir, const float* __restrict__ zp,
    const float* __restrict__ cl, const float* __restrict__ bc,
    const float* __restrict__ lnw, const float* __restrict__ lnb,
    const float* __restrict__ woutT, float* __restrict__ out) {
    __shared__ float comb[4][Ec];
    int wave = threadIdx.x >> 6, lane = threadIdx.x & 63;
    int row = blockIdx.x * 4 + wave;
    int b = row >> 12, lp = row & (Lc - 1);
    const float* y0 = ydir + ((size_t)(0 * Bc + b) * Lc + lp) * Ec;
    const float* y1 = ydir + ((size_t)(1 * Bc + b) * Lc + lp) * Ec;
    const float* y2 = ydir + ((size_t)(2 * Bc + b) * Lc + lp) * Ec;
    const float* y3 = ydir + ((size_t)(3 * Bc + b) * Lc + lp) * Ec;
    const float* zr = zp + ((size_t)b * Lc + lp) * Ec;
    const float* cr = cl + ((size_t)b * Lc + lp) * Ec;
    float ys[3], zv[3], cv[3];
    float s1 = 0, s2 = 0, z1 = 0, z2 = 0, c1 = 0, c2 = 0;
#pragma unroll
    for (int t = 0; t < 3; t++) {
        int i = lane + t * 64;
        float v = y0[i] + y1[i] + y2[i] + y3[i];
        ys[t] = v; s1 += v; s2 += v * v;
        float z = zr[i]; zv[t] = z; z1 += z; z2 += z * z;
        float c = cr[i]; cv[t] = c; c1 += c; c2 += c * c;
    }
#pragma unroll
    for (int o = 32; o >= 1; o >>= 1) {
        s1 += __shfl_xor(s1, o, 64); s2 += __shfl_xor(s2, o, 64);
        z1 += __shfl_xor(z1, o, 64); z2 += __shfl_xor(z2, o, 64);
        c1 += __shfl_xor(c1, o, 64); c2 += __shfl_xor(c2, o, 64);
    }
    const float invE = 1.f / (float)Ec;
    float ym = s1 * invE, yvr = rsqrtf(s2 * invE - ym * ym + 1e-5f);
    float zm = z1 * invE, zvr = rsqrtf(z2 * invE - zm * zm + 1e-5f);
    float cm = c1 * invE, cvr = rsqrtf(c2 * invE - cm * cm + 1e-5f);
#pragma unroll
    for (int t = 0; t < 3; t++) {
        int i = lane + t * 64;
        float g = lnw[i], bb = lnb[i];
        float a0 = (ys[t] - ym) * yvr * g + bb;
        float a1 = (zv[t] - zm) * zvr * g + bb;
        float a2 = (cv[t] - cm) * cvr * g + bb;
        float w0 = bc[i], w1 = bc[Ec + i], w2 = bc[2 * Ec + i];
        float mx = fmaxf(w0, fmaxf(w1, w2));
        float e0 = __expf(w0 - mx), e1 = __expf(w1 - mx), e2 = __expf(w2 - mx);
        float inv = 1.f / (e0 + e1 + e2);
        comb[wave][i] = (e0 * a0 + e1 * a1 + e2 * a2) * inv;
    }
    __syncthreads();
    float r0 = 0.f, r1 = 0.f;
#pragma unroll 4
    for (int k = 0; k < Ec; k++) {
        float cvk = comb[wave][k];
        float w0 = woutT[k * Cc + lane];
        float w1 = woutT[k * Cc + 64 + lane];
        r0 += cvk * w0;
        r1 += cvk * w1;
    }
    float* orow = out + (size_t)row * Cc;
    orow[lane] = r0;                      // o = 0..63, coalesced
    if (lane < 32) orow[64 + lane] = r1;  // o = 64..95, coalesced
}

extern "C" void kernel_launch(void* const* d_in, const int* in_sizes, int n_in,
                              void* d_out, int out_size, void* d_ws, size_t ws_size,
                              hipStream_t stream) {
    const float* x       = (const float*)d_in[0];
    const float* wh      = (const float*)d_in[3];
    const float* wv      = (const float*)d_in[4];
    const float* wd1     = (const float*)d_in[5];
    const float* wd2     = (const float*)d_in[6];
    const float* fw      = (const float*)d_in[7];
    const float* ipw     = (const float*)d_in[8];
    const float* xw      = (const float*)d_in[9];
    const float* dtw     = (const float*)d_in[10];
    const float* dtb     = (const float*)d_in[11];
    const float* A_log   = (const float*)d_in[12];
    const float* Dp      = (const float*)d_in[13];
    const float* dirB    = (const float*)d_in[14];
    const float* wout    = (const float*)d_in[15];
    const float* alphap  = (const float*)d_in[16];
    const float* betap   = (const float*)d_in[17];
    const float* fwp     = (const float*)d_in[18];
    const float* fbp     = (const float*)d_in[19];
    const float* vwp     = (const float*)d_in[20];
    const float* vbp     = (const float*)d_in[21];
    const float* pwp     = (const float*)d_in[22];
    const float* pbp     = (const float*)d_in[23];
    const float* clw     = (const float*)d_in[24];
    const float* clb     = (const float*)d_in[25];
    const float* bc      = (const float*)d_in[26];
    const float* lnw     = (const float*)d_in[27];
    const float* lnb     = (const float*)d_in[28];
    float* out = (float*)d_out;

    float* wsf = (float*)d_ws;
    size_t off = 0;
    int* ord      = (int*)wsf;             off += 4 * Lc;                 // 64 KB
    float* cat    = wsf + off;             off += (size_t)Bc * CATc * Lc; // 24 MB (reused as ydir)
    float* xconv  = wsf + off;             off += (size_t)Bc * Cc * Lc;   // 3 MB
    float* xp     = wsf + off;             off += (size_t)Bc * Lc * Ec;   // 6 MB (reused as c96T)
    float* zpb    = wsf + off;             off += (size_t)Bc * Lc * Ec;   // 6 MB
    float* deltab = wsf + off;             off += (size_t)Bc * Lc * Ec;   // 6 MB (reused as cl)
    float* BstT   = wsf + off;             off += (size_t)Bc * Lc * Nc;   // 0.5 MB
    float* CstT   = wsf + off;             off += (size_t)Bc * Lc * Nc;   // 0.5 MB
    float* hend   = wsf + off;             off += (size_t)4 * Bc * NCH * Ec * Nc; // 25.2 MB
    float* Pend   = wsf + off;             off += (size_t)Bc * NCH * Ec * Nc;     // 6.3 MB
    float* woutT  = wsf + off;             off += (size_t)Ec * Cc + 64;           // 74 KB
    float* fwT    = wsf + off;             off += (size_t)CATc * Cc;              // 288 KB
    float* xwT    = wsf + off;             off += (size_t)Ec * XJ + 64;           // 29 KB
    float* ipwT   = wsf + off;             off += (size_t)Cc * 2 * Ec;            // 144 KB
    float* clwT   = wsf + off;             off += (size_t)Cc * Ec;                // 72 KB
    // total ≈ 80.4 MB
    float* ydir = cat;     // cat dead after fuse; same size as ydir
    float* c96T = xp;      // xp dead after scan_part2 (stream-serialized)
    float* cl   = deltab;  // delta dead after scan_part2
    float* pxconv = xp;    // fuse partials span xp..hend-prefix (dead then)
    // xdbl intermediates alias hend (hend written only later by scan_part1):
    float* xpT  = hend;                                       // 192*8192 = 6 MB
    float* pxd  = hend + (size_t)Ec * Bc * Lc;                // 8*38*8192 ≈ 10 MB
    float* dt6R = pxd + (size_t)8 * XJ * Bc * Lc;             // 6*8192 = 192 KB

    setup_kernel<<<621, 256, 0, stream>>>(ord, wout, woutT, fw, fwT, xw, xwT,
                                          ipw, ipwT, clw, clwT);
    conv_kernel<<<dim3(16, 96, 2), 256, 0, stream>>>(x, wh, wv, wd1, wd2, cat);
    fuse_part<<<dim3(16, 8, 2), 256, 0, stream>>>(cat, fwT, pxconv);
    fuse_reduce<<<768, 256, 0, stream>>>(pxconv, xconv);
    inproj_kernel<<<dim3(16, 8, 2), 256, 0, stream>>>(xconv, ipwT, xp, zpb, xpT);
    xdbl_gemm<<<dim3(32, 8), 256, 0, stream>>>(xpT, xwT, pxd);
    xdbl_reduce<<<1216, 256, 0, stream>>>(pxd, dt6R, BstT, CstT);
    delta_kernel<<<8192, 192, 0, stream>>>(dt6R, dtw, dtb, deltab);
    scan_part1<<<dim3(NCH, 2), 192, 0, stream>>>(xp, ord, deltab, BstT,
                                                 A_log, dirB, hend, Pend);
    scan_mid<<<384, 64, 0, stream>>>(hend, Pend);
    scan_part2<<<dim3(NCH, 2), 192, 0, stream>>>(xp, ord, deltab, BstT, CstT,
                                                 A_log, Dp, dirB, hend, ydir);
    cluster_kernel<<<128, 256, 0, stream>>>(xconv, fwp, fbp, vwp, vbp, pwp, pbp,
                                            alphap, betap, c96T);
    clproj_kernel<<<dim3(16, 8, 2), 256, 0, stream>>>(c96T, clwT, clb, cl);
    final_kernel<<<2048, 256, 0, stream>>>(ydir, zpb, cl, bc, lnw, lnb, woutT, out);
}

// Round 11
// 335.336 us; speedup vs baseline: 1.0435x; 1.0435x over previous
//
#include <hip/hip_runtime.h>
#include <hip/hip_bf16.h>

#define Bc   2
#define Hc   64
#define Wc   64
#define Lc   4096
#define Cc   96
#define Ec   192
#define Nc   16
#define CATc 768
#define CHUNK 16
#define NCH  256
#define XJ   38
#define PF   8

// ---------------- scan-order closed forms (H=W=64) ----------------
__device__ __forceinline__ int inv_d0(int l) {           // bottom-up boustrophedon rows
    int i = l >> 6, j = l & 63;
    int k = 63 - i;
    int m = (k & 1) ? (63 - j) : j;
    return k * 64 + m;
}
__device__ __forceinline__ int inv_d1(int l) {           // left-right boustrophedon cols
    int i = l >> 6, j = l & 63;
    int m = (j & 1) ? (63 - i) : i;
    return j * 64 + m;
}
__device__ __forceinline__ int diag_off(int d) {
    return (d <= 63) ? (d * (d + 1) / 2) : (4096 - (127 - d) * (128 - d) / 2);
}
__device__ __forceinline__ int inv_d2(int l) {           // diagonals
    int i = l >> 6, j = l & 63;
    int d = i + j;
    int st = d > 63 ? d - 63 : 0;
    return diag_off(d) + (i - st);
}
__device__ __forceinline__ int inv_d3(int l) {           // anti-diagonals
    int i = l >> 6, jj = l & 63;
    int j = 63 - jj;
    int d = i + j;
    int st = d > 63 ? d - 63 : 0;
    return diag_off(d) + (i - st);
}

// setup: 0..15 ord; 16..87 wout^T; 88..375 fw^T; 376..404 xw^T;
//        405..548 ipw^T; 549..620 clw^T
__global__ __launch_bounds__(256) void setup_kernel(
    int* __restrict__ ord, const float* __restrict__ wout,
    float* __restrict__ woutT, const float* __restrict__ fw,
    float* __restrict__ fwT, const float* __restrict__ xw,
    float* __restrict__ xwT, const float* __restrict__ ipw,
    float* __restrict__ ipwT, const float* __restrict__ clw,
    float* __restrict__ clwT) {
    if (blockIdx.x < 16) {
        int l = blockIdx.x * 256 + threadIdx.x;
        ord[0 * Lc + inv_d0(l)] = l;
        ord[1 * Lc + inv_d1(l)] = l;
        ord[2 * Lc + inv_d2(l)] = l;
        ord[3 * Lc + inv_d3(l)] = l;
    } else if (blockIdx.x < 88) {
        int idx = (blockIdx.x - 16) * 256 + threadIdx.x;
        if (idx < Ec * Cc) {
            int k = idx / Cc, o = idx % Cc;
            woutT[idx] = wout[o * Ec + k];
        }
    } else if (blockIdx.x < 376) {
        int idx = (blockIdx.x - 88) * 256 + threadIdx.x;   // 288 blocks = 73728
        int k = idx / Cc, o = idx % Cc;                    // fwT[k][o] = fw[o][k]
        fwT[idx] = fw[o * CATc + k];
    } else if (blockIdx.x < 405) {
        int idx = (blockIdx.x - 376) * 256 + threadIdx.x;  // 29 blocks, 7296 elems
        if (idx < Ec * XJ) {
            int c = idx / XJ, j = idx % XJ;                // xwT[c][j] = xw[j][c]
            xwT[idx] = xw[j * Ec + c];
        }
    } else if (blockIdx.x < 549) {
        int idx = (blockIdx.x - 405) * 256 + threadIdx.x;  // 144 blocks = 36864
        int c = idx / (2 * Ec), o = idx % (2 * Ec);        // ipwT[c][o] = ipw[o][c]
        ipwT[idx] = ipw[o * Cc + c];
    } else {
        int idx = (blockIdx.x - 549) * 256 + threadIdx.x;  // 72 blocks = 18432
        int c = idx / Ec, o = idx % Ec;                    // clwT[c][o] = clw[o][c]
        clwT[idx] = clw[o * Cc + c];
    }
}

// ---------------- directional convs + SiLU -> cat [B,768,L] ----------------
__global__ __launch_bounds__(256) void conv_kernel(
    const float* __restrict__ x, const float* __restrict__ wh,
    const float* __restrict__ wv, const float* __restrict__ wd1,
    const float* __restrict__ wd2, float* __restrict__ cat) {
    int tile = blockIdx.x, ic = blockIdx.y, b = blockIdx.z;
    int th0 = (tile >> 2) * 16, tw0 = (tile & 3) * 16;
    __shared__ float S[22][24];
    int tid = threadIdx.x;
    for (int idx = tid; idx < 22 * 22; idx += 256) {
        int r = idx / 22, c = idx % 22;
        int gh = th0 + r - 3, gw = tw0 + c - 3;
        float v = 0.f;
        if (gh >= 0 && gh < 64 && gw >= 0 && gw < 64)
            v = x[((size_t)b * Lc + gh * 64 + gw) * Cc + ic];
        S[r][c] = v;
    }
    __syncthreads();
    int ti = tid >> 4, tj = tid & 15;
    int pix = (th0 + ti) * 64 + (tw0 + tj);
    for (int s = 0; s < 2; s++) {
        int o = 2 * ic + s;
        float ah = 0.f, av = 0.f, a1 = 0.f, a2 = 0.f;
#pragma unroll
        for (int t = 0; t < 7; t++) {
            ah += S[ti + 3][tj + t] * wh[o * 7 + t];
            av += S[ti + t][tj + 3] * wv[o * 7 + t];
        }
#pragma unroll
        for (int r = 0; r < 7; r++)
#pragma unroll
            for (int c2 = 0; c2 < 7; c2++) {
                float sv = S[ti + r][tj + c2];
                a1 += sv * wd1[o * 49 + r * 7 + c2];
                a2 += sv * wd2[o * 49 + r * 7 + c2];
            }
        cat[((size_t)b * CATc + 0 * Ec + o) * Lc + pix] = ah / (1.f + __expf(-ah));
        cat[((size_t)b * CATc + 1 * Ec + o) * Lc + pix] = av / (1.f + __expf(-av));
        cat[((size_t)b * CATc + 2 * Ec + o) * Lc + pix] = a1 / (1.f + __expf(-a1));
        cat[((size_t)b * CATc + 3 * Ec + o) * Lc + pix] = a2 / (1.f + __expf(-a2));
    }
}

// ---------------- fuse v3 (REVERTED from v4): 48-o slice, scalar fwT loads ----------------
// R10 lesson: 96-acc v4 spilled (VGPR_Count=56 < ~110 live) -> 49 us. 48 acc sits
// under the allocator's cliff (no spill, ~13 us). Static indexing forces liveness
// but NOT a bigger register file — keep per-thread acc <= ~48.
__global__ __launch_bounds__(256) void fuse_part(
    const float* __restrict__ cat, const float* __restrict__ fwT,
    float* __restrict__ pxconv) {
    int l  = blockIdx.x * 256 + threadIdx.x;   // 0..4095 within batch
    int kc = blockIdx.y;                        // 8 chunks of 96 k
    int b  = blockIdx.z >> 1;
    int o0 = (blockIdx.z & 1) * 48;             // uniform -> scalar weight path
    float acc[48];
#pragma unroll
    for (int j = 0; j < 48; j++) acc[j] = 0.f;
    const float* csrc = cat + ((size_t)b * CATc + kc * 96) * Lc + l;
    const float* wsrc = fwT + (size_t)(kc * 96) * Cc + o0;
#pragma unroll 4
    for (int k = 0; k < 96; k++) {
        float v = csrc[(size_t)k * Lc];
        const float* wr = wsrc + (size_t)k * Cc;
#pragma unroll
        for (int j = 0; j < 48; j++) acc[j] += v * wr[j];
    }
    float* dst = pxconv + (((size_t)kc * Bc + b) * Cc + o0) * Lc + l;
#pragma unroll
    for (int j = 0; j < 48; j++) dst[(size_t)j * Lc] = acc[j];
}

__global__ __launch_bounds__(256) void fuse_reduce(
    const float* __restrict__ pxconv, float* __restrict__ xconv) {
    size_t idx = ((size_t)blockIdx.x * 256 + threadIdx.x) * 4;   // float4 over Bc*Cc*Lc
    const size_t stride = (size_t)Bc * Cc * Lc;
    float4 s = *(const float4*)(pxconv + idx);
#pragma unroll
    for (int k = 1; k < 8; k++) {
        float4 v = *(const float4*)(pxconv + idx + (size_t)k * stride);
        s.x += v.x; s.y += v.y; s.z += v.z; s.w += v.w;
    }
    *(float4*)(xconv + idx) = s;
}

// ---------------- in_proj v3: 48-o slices, scalar ipwT ----------------
__global__ __launch_bounds__(256) void inproj_kernel(
    const float* __restrict__ xconv, const float* __restrict__ ipwT,
    float* __restrict__ xp, float* __restrict__ zp, float* __restrict__ xpT) {
    int l = blockIdx.x * 256 + threadIdx.x;
    int o0 = blockIdx.y * 48;              // 8 groups: 0..3 -> xp, 4..7 -> zp
    int b = blockIdx.z;
    float acc[48];
#pragma unroll
    for (int j = 0; j < 48; j++) acc[j] = 0.f;
    const float* csrc = xconv + (size_t)b * Cc * Lc + l;
    const float* wsrc = ipwT + o0;
#pragma unroll 4
    for (int c = 0; c < Cc; c++) {
        float v = csrc[(size_t)c * Lc];
        const float* wr = wsrc + c * (2 * Ec);   // uniform -> s_load
#pragma unroll
        for (int j = 0; j < 48; j++) acc[j] += v * wr[j];
    }
    if (o0 < Ec) {
        float* xr = xp + ((size_t)b * Lc + l) * Ec + o0;
#pragma unroll
        for (int j = 0; j < 48; j++) xr[j] = acc[j];
        float* xt = xpT + (size_t)o0 * (Bc * Lc) + b * Lc + l;
#pragma unroll
        for (int j = 0; j < 48; j++) xt[(size_t)j * (Bc * Lc)] = acc[j];  // coalesced
    } else {
        float* zr = zp + ((size_t)b * Lc + l) * Ec + (o0 - Ec);
#pragma unroll
        for (int j = 0; j < 48; j++) zr[j] = acc[j];
    }
}

// ---------------- xdbl GEMM v2: thread-owns-row, scalar xwT, split-K 8 ----------------
// pxd layout [kc][j][r], r = b*Lc + l flat (8192)
__global__ __launch_bounds__(256) void xdbl_gemm(
    const float* __restrict__ xpT, const float* __restrict__ xwT,
    float* __restrict__ pxd) {
    int r  = blockIdx.x * 256 + threadIdx.x;   // 0..8191
    int kc = blockIdx.y;                        // 8 chunks of 24 k
    float acc[XJ];
#pragma unroll
    for (int j = 0; j < XJ; j++) acc[j] = 0.f;
    const float* src = xpT + (size_t)(kc * 24) * (Bc * Lc) + r;
    const float* w   = xwT + kc * 24 * XJ;
#pragma unroll 4
    for (int k = 0; k < 24; k++) {
        float v = src[(size_t)k * (Bc * Lc)];
        const float* wr = w + k * XJ;           // uniform -> s_load
#pragma unroll
        for (int j = 0; j < XJ; j++) acc[j] += v * wr[j];
    }
    float* dst = pxd + (size_t)kc * XJ * (Bc * Lc) + r;
#pragma unroll
    for (int j = 0; j < XJ; j++) dst[(size_t)j * (Bc * Lc)] = acc[j];
}

// reduce 8 partials -> dt6R [6][8192], BstT/CstT [b][n][l]
__global__ __launch_bounds__(256) void xdbl_reduce(
    const float* __restrict__ pxd, float* __restrict__ dt6R,
    float* __restrict__ BstT, float* __restrict__ CstT) {
    int idx = blockIdx.x * 256 + threadIdx.x;   // j*8192 + r, exactly 38*8192
    float s = 0.f;
#pragma unroll
    for (int kc = 0; kc < 8; kc++) s += pxd[(size_t)kc * XJ * (Bc * Lc) + idx];
    int j = idx >> 13, r = idx & (Bc * Lc - 1);
    int b = r >> 12, l = r & (Lc - 1);
    if (j < 6)       dt6R[j * (Bc * Lc) + r] = s;
    else if (j < 22) BstT[((size_t)b * Nc + (j - 6)) * Lc + l] = s;
    else             CstT[((size_t)b * Nc + (j - 22)) * Lc + l] = s;
}

// delta[row][e] = softplus(dt6R[.][row] @ dtw^T + 2*dtb)   (coalesced writes)
__global__ __launch_bounds__(192) void delta_kernel(
    const float* __restrict__ dt6R, const float* __restrict__ dtw,
    const float* __restrict__ dtb, float* __restrict__ delta) {
    int r = blockIdx.x;          // 0..8191 flat row
    int e = threadIdx.x;         // 0..191
    const float* w = dtw + e * 6;
    float s = 2.f * dtb[e];
#pragma unroll
    for (int rr = 0; rr < 6; rr++) s += dt6R[rr * (Bc * Lc) + r] * w[rr];
    delta[(size_t)r * Ec + e] = (s > 20.f) ? s : __logf(1.f + __expf(s));
}

// ============ chunked selective scan, d-FUSED, PREFETCHED ============

__global__ __launch_bounds__(192, 2) void scan_part1(
    const float* __restrict__ xp, const int* __restrict__ ord,
    const float* __restrict__ delta, const float* __restrict__ BstT,
    const float* __restrict__ A_log, const float* __restrict__ dirB,
    float* __restrict__ hend, float* __restrict__ Pend) {
    int chunk = blockIdx.x, b = blockIdx.y;
    int e = threadIdx.x;                 // 0..191
    int l0 = chunk * CHUNK;
    __shared__ int lord[4][CHUNK];
    __shared__ float4 Bs[CHUNK][Nc];     // (B[n][l] + dirB[d][n]) packed over d
    if (threadIdx.x < 64) {
        int d = threadIdx.x >> 4, t = threadIdx.x & 15;
        lord[d][t] = ord[d * Lc + l0 + t];
    }
    {
        const float* Bb = BstT + (size_t)b * Nc * Lc;
        for (int idx = threadIdx.x; idx < CHUNK * Nc; idx += 192) {
            int n = idx >> 4, t = idx & 15;
            float Bn = Bb[(size_t)n * Lc + l0 + t];
            Bs[t][n] = make_float4(Bn + dirB[0 * Nc + n], Bn + dirB[1 * Nc + n],
                                   Bn + dirB[2 * Nc + n], Bn + dirB[3 * Nc + n]);
        }
    }
    __syncthreads();
    const float* dl  = delta + (size_t)b * Lc * Ec + e;
    const float* xpb = xp + (size_t)b * Lc * Ec + e;
    float de[CHUNK], u0[CHUNK], u1[CHUNK], u2[CHUNK], u3[CHUNK];
#pragma unroll
    for (int t = 0; t < CHUNK; t++) de[t] = dl[(size_t)(l0 + t) * Ec];
#pragma unroll
    for (int t = 0; t < CHUNK; t++) {
        u0[t] = xpb[(size_t)lord[0][t] * Ec];
        u1[t] = xpb[(size_t)lord[1][t] * Ec];
        u2[t] = xpb[(size_t)lord[2][t] * Ec];
        u3[t] = xpb[(size_t)lord[3][t] * Ec];
    }
    float Aen[Nc], P[Nc], h0[Nc], h1[Nc], h2[Nc], h3[Nc];
#pragma unroll
    for (int n = 0; n < Nc; n++) {
        Aen[n] = -__expf(A_log[e * Nc + n]);
        P[n] = 1.f; h0[n] = 0.f; h1[n] = 0.f; h2[n] = 0.f; h3[n] = 0.f;
    }
#pragma unroll
    for (int t = 0; t < CHUNK; t++) {
        float du0 = de[t] * u0[t], du1 = de[t] * u1[t];
        float du2 = de[t] * u2[t], du3 = de[t] * u3[t];
#pragma unroll
        for (int n = 0; n < Nc; n++) {
            float dA = __expf(de[t] * Aen[n]);             // ONE exp for 4 dirs
            float4 B4 = Bs[t][n];                          // LDS broadcast
            P[n] *= dA;
            h0[n] = dA * h0[n] + du0 * B4.x;
            h1[n] = dA * h1[n] + du1 * B4.y;
            h2[n] = dA * h2[n] + du2 * B4.z;
            h3[n] = dA * h3[n] + du3 * B4.w;
        }
    }
    size_t cb = ((size_t)b * NCH + chunk) * 3072 + e;
    const size_t dstr = (size_t)Bc * NCH * 3072;
#pragma unroll
    for (int n = 0; n < Nc; n++) {
        hend[cb + 0 * dstr + n * Ec] = h0[n];
        hend[cb + 1 * dstr + n * Ec] = h1[n];
        hend[cb + 2 * dstr + n * Ec] = h2[n];
        hend[cb + 3 * dstr + n * Ec] = h3[n];
        Pend[cb + n * Ec] = P[n];
    }
}

// 384 blocks x 64 thr; 8-deep software pipeline.
__global__ __launch_bounds__(64) void scan_mid(
    float* __restrict__ hend, const float* __restrict__ Pend) {
    int blk = blockIdx.x;            // db*48 + sub
    int sub = blk % 48, db = blk / 48;
    int b = db & 1;
    int pair = sub * 64 + threadIdx.x;   // 0..3071 = (n,e) flat
    size_t base  = (size_t)db * NCH * 3072 + pair;
    size_t pbase = (size_t)b * NCH * 3072 + pair;
    float hbuf[PF], Pbuf[PF];
#pragma unroll
    for (int i = 0; i < PF; i++) {
        hbuf[i] = hend[base + (size_t)i * 3072];
        Pbuf[i] = Pend[pbase + (size_t)i * 3072];
    }
    float h = 0.f;
    for (int c = 0; c < NCH; c += PF) {
#pragma unroll
        for (int i = 0; i < PF; i++) {
            float hc = hbuf[i], P = Pbuf[i];
            int cn = c + i + PF;
            if (cn < NCH) {
                hbuf[i] = hend[base + (size_t)cn * 3072];
                Pbuf[i] = Pend[pbase + (size_t)cn * 3072];
            }
            hend[base + (size_t)(c + i) * 3072] = h;   // h_in for chunk c+i
            h = P * h + hc;
        }
    }
}

// scan_part2 v2: writes y directly at SPATIAL position (lord[d][t]) — bijective
// scatter, rows stay per-row coalesced; final_kernel reads all streams at lp.
__global__ __launch_bounds__(192, 2) void scan_part2(
    const float* __restrict__ xp, const int* __restrict__ ord,
    const float* __restrict__ delta, const float* __restrict__ BstT,
    const float* __restrict__ CstT, const float* __restrict__ A_log,
    const float* __restrict__ Dp, const float* __restrict__ dirB,
    const float* __restrict__ hend, float* __restrict__ ydir) {
    int chunk = blockIdx.x, b = blockIdx.y;
    int e = threadIdx.x;                 // 0..191
    int l0 = chunk * CHUNK;
    __shared__ int lord[4][CHUNK];
    __shared__ float4 Bs[CHUNK][Nc];
    __shared__ float Cs[CHUNK][Nc];
    if (threadIdx.x < 64) {
        int d = threadIdx.x >> 4, t = threadIdx.x & 15;
        lord[d][t] = ord[d * Lc + l0 + t];
    }
    {
        const float* Bb = BstT + (size_t)b * Nc * Lc;
        const float* Cb = CstT + (size_t)b * Nc * Lc;
        for (int idx = threadIdx.x; idx < CHUNK * Nc; idx += 192) {
            int n = idx >> 4, t = idx & 15;
            float Bn = Bb[(size_t)n * Lc + l0 + t];
            Bs[t][n] = make_float4(Bn + dirB[0 * Nc + n], Bn + dirB[1 * Nc + n],
                                   Bn + dirB[2 * Nc + n], Bn + dirB[3 * Nc + n]);
            Cs[t][n] = Cb[(size_t)n * Lc + l0 + t];
        }
    }
    __syncthreads();
    const float* dl  = delta + (size_t)b * Lc * Ec + e;
    const float* xpb = xp + (size_t)b * Lc * Ec + e;
    float de[CHUNK], u0[CHUNK], u1[CHUNK], u2[CHUNK], u3[CHUNK];
#pragma unroll
    for (int t = 0; t < CHUNK; t++) de[t] = dl[(size_t)(l0 + t) * Ec];
#pragma unroll
    for (int t = 0; t < CHUNK; t++) {
        u0[t] = xpb[(size_t)lord[0][t] * Ec];
        u1[t] = xpb[(size_t)lord[1][t] * Ec];
        u2[t] = xpb[(size_t)lord[2][t] * Ec];
        u3[t] = xpb[(size_t)lord[3][t] * Ec];
    }
    float Aen[Nc], h0[Nc], h1[Nc], h2[Nc], h3[Nc];
    size_t cb = ((size_t)b * NCH + chunk) * 3072 + e;
    const size_t dstr = (size_t)Bc * NCH * 3072;
#pragma unroll
    for (int n = 0; n < Nc; n++) {
        Aen[n] = -__expf(A_log[e * Nc + n]);
        h0[n] = hend[cb + 0 * dstr + n * Ec];
        h1[n] = hend[cb + 1 * dstr + n * Ec];
        h2[n] = hend[cb + 2 * dstr + n * Ec];
        h3[n] = hend[cb + 3 * dstr + n * Ec];
    }
    float De = Dp[e];
    float* yo0 = ydir + ((size_t)(0 * Bc + b) * Lc) * Ec + e;
    float* yo1 = ydir + ((size_t)(1 * Bc + b) * Lc) * Ec + e;
    float* yo2 = ydir + ((size_t)(2 * Bc + b) * Lc) * Ec + e;
    float* yo3 = ydir + ((size_t)(3 * Bc + b) * Lc) * Ec + e;
#pragma unroll
    for (int t = 0; t < CHUNK; t++) {
        float du0 = de[t] * u0[t], du1 = de[t] * u1[t];
        float du2 = de[t] * u2[t], du3 = de[t] * u3[t];
        float a0 = De * u0[t], a1 = De * u1[t];
        float a2 = De * u2[t], a3 = De * u3[t];
#pragma unroll
        for (int n = 0; n < Nc; n++) {
            float dA = __expf(de[t] * Aen[n]);             // ONE exp for 4 dirs
            float4 B4 = Bs[t][n];
            float Cn = Cs[t][n];
            h0[n] = dA * h0[n] + du0 * B4.x;
            h1[n] = dA * h1[n] + du1 * B4.y;
            h2[n] = dA * h2[n] + du2 * B4.z;
            h3[n] = dA * h3[n] + du3 * B4.w;
            a0 += h0[n] * Cn; a1 += h1[n] * Cn;
            a2 += h2[n] * Cn; a3 += h3[n] * Cn;
        }
        yo0[(size_t)lord[0][t] * Ec] = a0;    // scatter to spatial order
        yo1[(size_t)lord[1][t] * Ec] = a1;
        yo2[(size_t)lord[2][t] * Ec] = a2;
        yo3[(size_t)lord[3][t] * Ec] = a3;
    }
}

// ---------------- local cluster v2: 256 threads/block ----------------
__global__ __launch_bounds__(256) void cluster_kernel(
    const float* __restrict__ xconv,
    const float* __restrict__ fwp, const float* __restrict__ fbp,
    const float* __restrict__ vwp, const float* __restrict__ vbp,
    const float* __restrict__ pwp, const float* __restrict__ pbp,
    const float* __restrict__ alphap, const float* __restrict__ betap,
    float* __restrict__ c96T) {
    int g = blockIdx.x;
    int b = g >> 6, Wg = (g >> 3) & 7, Hg = g & 7;
    int tid = threadIdx.x;
    int p = tid & 63, q = tid >> 6;
    int wi = p >> 3, hj = p & 7;
    int lsp = (Wg * 8 + wi) * 64 + (Hg * 8 + hj);
    __shared__ float fS[64][6], vS[64][6];
    __shared__ float fP[4][64][6], vP[4][64][6];
    __shared__ float cen[25][6], vc[25][6], cnorm[25];
    __shared__ float simb[64];
    __shared__ int kb[64];
    __shared__ float aggP[4][25][8];     // [q][k][0..5]=sum s*v, [6]=sum_s
    __shared__ float agg[25][6];
    // phase A: input proj, 12 c's per (p,q)
    float fr[6], vr[6];
#pragma unroll
    for (int oc = 0; oc < 6; oc++) { fr[oc] = 0.f; vr[oc] = 0.f; }
    for (int c = q * 12; c < q * 12 + 12; c++) {
        float v1 = xconv[((size_t)b * Cc + c) * Lc + lsp];
        float v2 = xconv[((size_t)b * Cc + 48 + c) * Lc + lsp];
#pragma unroll
        for (int oc = 0; oc < 6; oc++) {
            fr[oc] += v1 * fwp[oc * 48 + c];
            vr[oc] += v2 * vwp[oc * 48 + c];
        }
    }
#pragma unroll
    for (int oc = 0; oc < 6; oc++) { fP[q][p][oc] = fr[oc]; vP[q][p][oc] = vr[oc]; }
    __syncthreads();
    if (q == 0) {
#pragma unroll
        for (int oc = 0; oc < 6; oc++) {
            fS[p][oc] = fbp[oc] + fP[0][p][oc] + fP[1][p][oc] + fP[2][p][oc] + fP[3][p][oc];
            vS[p][oc] = vbp[oc] + vP[0][p][oc] + vP[1][p][oc] + vP[2][p][oc] + vP[3][p][oc];
        }
    }
    __syncthreads();
    // phase B: adaptive-pool bins for 8->5 (150 items over 256 threads)
    const int bs[5] = {0, 1, 3, 4, 6}, be[5] = {2, 4, 5, 7, 8};
    if (tid < 150) {
        int k = tid / 6, oc = tid % 6;
        int ki = k / 5, kj = k % 5;
        float sf = 0.f, sv = 0.f;
        int cnt = 0;
        for (int ii = bs[ki]; ii < be[ki]; ii++)
            for (int jj = bs[kj]; jj < be[kj]; jj++) {
                sf += fS[ii * 8 + jj][oc];
                sv += vS[ii * 8 + jj][oc];
                cnt++;
            }
        cen[k][oc] = sf / cnt;
        vc[k][oc] = sv / cnt;
    }
    __syncthreads();
    if (tid < 25) {
        float s = 0.f;
#pragma unroll
        for (int oc = 0; oc < 6; oc++) s += cen[tid][oc] * cen[tid][oc];
        cnorm[tid] = 1.f / fmaxf(sqrtf(s), 1e-12f);
    }
    __syncthreads();
    // phase C: per-p argmax over 25 centers (first-occurrence semantics)
    if (q == 0) {
        float f2[6];
#pragma unroll
        for (int oc = 0; oc < 6; oc++) f2[oc] = fS[p][oc];
        float fn2 = 0.f;
#pragma unroll
        for (int oc = 0; oc < 6; oc++) fn2 += f2[oc] * f2[oc];
        float finv = 1.f / fmaxf(sqrtf(fn2), 1e-12f);
        float alpha = alphap[0], beta = betap[0];
        float best = -1.f;
        int bestk = 0;
        for (int k = 0; k < 25; k++) {
            float dot = 0.f;
#pragma unroll
            for (int oc = 0; oc < 6; oc++) dot += cen[k][oc] * f2[oc];
            float xv = beta + alpha * dot * cnorm[k] * finv;
            float s = 1.f / (1.f + __expf(-xv));
            if (s > best) { best = s; bestk = k; }
        }
        simb[p] = best;
        kb[p] = bestk;
    }
    __syncthreads();
    // phase D: agg — each (p<25, q) scans 16 of the 64 positions
    if (p < 25) {
        float sum_s = 0.f;
        float av[6];
#pragma unroll
        for (int oc = 0; oc < 6; oc++) av[oc] = 0.f;
        for (int qq = q * 16; qq < q * 16 + 16; qq++) {
            if (kb[qq] == p) {
                float s = simb[qq];
                sum_s += s;
#pragma unroll
                for (int oc = 0; oc < 6; oc++) av[oc] += s * vS[qq][oc];
            }
        }
#pragma unroll
        for (int oc = 0; oc < 6; oc++) aggP[q][p][oc] = av[oc];
        aggP[q][p][6] = sum_s;
    }
    __syncthreads();
    if (q == 0 && p < 25) {
        float sum_s = aggP[0][p][6] + aggP[1][p][6] + aggP[2][p][6] + aggP[3][p][6];
        float invd = 1.f / (sum_s + 1.f);
#pragma unroll
        for (int oc = 0; oc < 6; oc++)
            agg[p][oc] = (vc[p][oc] + aggP[0][p][oc] + aggP[1][p][oc] +
                          aggP[2][p][oc] + aggP[3][p][oc]) * invd;
    }
    __syncthreads();
    // phase E: output proj, 24 oo's per (p,q)
    float outp[6];
    {
        int k = kb[p];
        float s = simb[p];
#pragma unroll
        for (int oc = 0; oc < 6; oc++) outp[oc] = agg[k][oc] * s;
    }
    float* ocol = c96T + (size_t)b * Cc * Lc + lsp;
    for (int oo = q * 24; oo < q * 24 + 24; oo++) {
        float s = pbp[oo];
#pragma unroll
        for (int oc = 0; oc < 6; oc++) s += outp[oc] * pwp[oo * 6 + oc];
        ocol[(size_t)oo * Lc] = s;           // c96T[b][oo][lsp]
    }
}

// ---------------- cluster projection v2: c96T input, scalar clwT, 24-o slices ----------------
__global__ __launch_bounds__(256) void clproj_kernel(
    const float* __restrict__ c96T, const float* __restrict__ clwT,
    const float* __restrict__ bias, float* __restrict__ cl) {
    int l = blockIdx.x * 256 + threadIdx.x;
    int o0 = blockIdx.y * 24;              // 8 groups
    int b = blockIdx.z;
    float acc[24];
#pragma unroll
    for (int j = 0; j < 24; j++) acc[j] = bias[o0 + j];
    const float* csrc = c96T + (size_t)b * Cc * Lc + l;
    const float* wsrc = clwT + o0;
#pragma unroll 4
    for (int c = 0; c < Cc; c++) {
        float v = csrc[(size_t)c * Lc];
        const float* wr = wsrc + c * Ec;       // uniform -> s_load
#pragma unroll
        for (int j = 0; j < 24; j++) acc[j] += v * wr[j];
    }
    float* cr = cl + ((size_t)b * Lc + l) * Ec + o0;
#pragma unroll
    for (int j = 0; j < 24; j++) cr[j] = acc[j];
}

// ---------------- y sum (all at row lp) + 3x LayerNorm + branch softmax + out_proj ----------------
__global__ __launch_bounds__(256) void final_kernel(
    const float* __restrict__ ydir, const float* __restrict__ zp,
    const float* __restrict__ cl, const float* __restrict__ bc,
    const float* __restrict__ lnw, const float* __restrict__ lnb,
    const float* __restrict__ woutT, float* __restrict__ out) {
    __shared__ float comb[4][Ec];
    int wave = threadIdx.x >> 6, lane = threadIdx.x & 63;
    int row = blockIdx.x * 4 + wave;
    int b = row >> 12, lp = row & (Lc - 1);
    const float* y0 = ydir + ((size_t)(0 * Bc + b) * Lc + lp) * Ec;
    const float* y1 = ydir + ((size_t)(1 * Bc + b) * Lc + lp) * Ec;
    const float* y2 = ydir + ((size_t)(2 * Bc + b) * Lc + lp) * Ec;
    const float* y3 = ydir + ((size_t)(3 * Bc + b) * Lc + lp) * Ec;
    const float* zr = zp + ((size_t)b * Lc + lp) * Ec;
    const float* cr = cl + ((size_t)b * Lc + lp) * Ec;
    float ys[3], zv[3], cv[3];
    float s1 = 0, s2 = 0, z1 = 0, z2 = 0, c1 = 0, c2 = 0;
#pragma unroll
    for (int t = 0; t < 3; t++) {
        int i = lane + t * 64;
        float v = y0[i] + y1[i] + y2[i] + y3[i];
        ys[t] = v; s1 += v; s2 += v * v;
        float z = zr[i]; zv[t] = z; z1 += z; z2 += z * z;
        float c = cr[i]; cv[t] = c; c1 += c; c2 += c * c;
    }
#pragma unroll
    for (int o = 32; o >= 1; o >>= 1) {
        s1 += __shfl_xor(s1, o, 64); s2 += __shfl_xor(s2, o, 64);
        z1 += __shfl_xor(z1, o, 64); z2 += __shfl_xor(z2, o, 64);
        c1 += __shfl_xor(c1, o, 64); c2 += __shfl_xor(c2, o, 64);
    }
    const float invE = 1.f / (float)Ec;
    float ym = s1 * invE, yvr = rsqrtf(s2 * invE - ym * ym + 1e-5f);
    float zm = z1 * invE, zvr = rsqrtf(z2 * invE - zm * zm + 1e-5f);
    float cm = c1 * invE, cvr = rsqrtf(c2 * invE - cm * cm + 1e-5f);
#pragma unroll
    for (int t = 0; t < 3; t++) {
        int i = lane + t * 64;
        float g = lnw[i], bb = lnb[i];
        float a0 = (ys[t] - ym) * yvr * g + bb;
        float a1 = (zv[t] - zm) * zvr * g + bb;
        float a2 = (cv[t] - cm) * cvr * g + bb;
        float w0 = bc[i], w1 = bc[Ec + i], w2 = bc[2 * Ec + i];
        float mx = fmaxf(w0, fmaxf(w1, w2));
        float e0 = __expf(w0 - mx), e1 = __expf(w1 - mx), e2 = __expf(w2 - mx);
        float inv = 1.f / (e0 + e1 + e2);
        comb[wave][i] = (e0 * a0 + e1 * a1 + e2 * a2) * inv;
    }
    __syncthreads();
    float r0 = 0.f, r1 = 0.f;
#pragma unroll 4
    for (int k = 0; k < Ec; k++) {
        float cvk = comb[wave][k];
        float w0 = woutT[k * Cc + lane];
        float w1 = woutT[k * Cc + 64 + lane];
        r0 += cvk * w0;
        r1 += cvk * w1;
    }
    float* orow = out + (size_t)row * Cc;
    orow[lane] = r0;                      // o = 0..63, coalesced
    if (lane < 32) orow[64 + lane] = r1;  // o = 64..95, coalesced
}

extern "C" void kernel_launch(void* const* d_in, const int* in_sizes, int n_in,
                              void* d_out, int out_size, void* d_ws, size_t ws_size,
                              hipStream_t stream) {
    const float* x       = (const float*)d_in[0];
    const float* wh      = (const float*)d_in[3];
    const float* wv      = (const float*)d_in[4];
    const float* wd1     = (const float*)d_in[5];
    const float* wd2     = (const float*)d_in[6];
    const float* fw      = (const float*)d_in[7];
    const float* ipw     = (const float*)d_in[8];
    const float* xw      = (const float*)d_in[9];
    const float* dtw     = (const float*)d_in[10];
    const float* dtb     = (const float*)d_in[11];
    const float* A_log   = (const float*)d_in[12];
    const float* Dp      = (const float*)d_in[13];
    const float* dirB    = (const float*)d_in[14];
    const float* wout    = (const float*)d_in[15];
    const float* alphap  = (const float*)d_in[16];
    const float* betap   = (const float*)d_in[17];
    const float* fwp     = (const float*)d_in[18];
    const float* fbp     = (const float*)d_in[19];
    const float* vwp     = (const float*)d_in[20];
    const float* vbp     = (const float*)d_in[21];
    const float* pwp     = (const float*)d_in[22];
    const float* pbp     = (const float*)d_in[23];
    const float* clw     = (const float*)d_in[24];
    const float* clb     = (const float*)d_in[25];
    const float* bc      = (const float*)d_in[26];
    const float* lnw     = (const float*)d_in[27];
    const float* lnb     = (const float*)d_in[28];
    float* out = (float*)d_out;

    float* wsf = (float*)d_ws;
    size_t off = 0;
    int* ord      = (int*)wsf;             off += 4 * Lc;                 // 64 KB
    float* cat    = wsf + off;             off += (size_t)Bc * CATc * Lc; // 24 MB (reused as ydir)
    float* xconv  = wsf + off;             off += (size_t)Bc * Cc * Lc;   // 3 MB
    float* xp     = wsf + off;             off += (size_t)Bc * Lc * Ec;   // 6 MB (reused as c96T)
    float* zpb    = wsf + off;             off += (size_t)Bc * Lc * Ec;   // 6 MB
    float* deltab = wsf + off;             off += (size_t)Bc * Lc * Ec;   // 6 MB (reused as cl)
    float* BstT   = wsf + off;             off += (size_t)Bc * Lc * Nc;   // 0.5 MB
    float* CstT   = wsf + off;             off += (size_t)Bc * Lc * Nc;   // 0.5 MB
    float* hend   = wsf + off;             off += (size_t)4 * Bc * NCH * Ec * Nc; // 25.2 MB
    float* Pend   = wsf + off;             off += (size_t)Bc * NCH * Ec * Nc;     // 6.3 MB
    float* woutT  = wsf + off;             off += (size_t)Ec * Cc + 64;           // 74 KB
    float* fwT    = wsf + off;             off += (size_t)CATc * Cc;              // 288 KB
    float* xwT    = wsf + off;             off += (size_t)Ec * XJ + 64;           // 29 KB
    float* ipwT   = wsf + off;             off += (size_t)Cc * 2 * Ec;            // 144 KB
    float* clwT   = wsf + off;             off += (size_t)Cc * Ec;                // 72 KB
    // total ≈ 80.4 MB
    float* ydir = cat;     // cat dead after fuse; same size as ydir
    float* c96T = xp;      // xp dead after scan_part2 (stream-serialized)
    float* cl   = deltab;  // delta dead after scan_part2
    float* pxconv = xp;    // fuse partials span xp..hend-prefix (dead then)
    // xdbl intermediates alias hend (hend written only later by scan_part1):
    float* xpT  = hend;                                       // 192*8192 = 6 MB
    float* pxd  = hend + (size_t)Ec * Bc * Lc;                // 8*38*8192 ≈ 10 MB
    float* dt6R = pxd + (size_t)8 * XJ * Bc * Lc;             // 6*8192 = 192 KB

    setup_kernel<<<621, 256, 0, stream>>>(ord, wout, woutT, fw, fwT, xw, xwT,
                                          ipw, ipwT, clw, clwT);
    conv_kernel<<<dim3(16, 96, 2), 256, 0, stream>>>(x, wh, wv, wd1, wd2, cat);
    fuse_part<<<dim3(16, 8, 4), 256, 0, stream>>>(cat, fwT, pxconv);
    fuse_reduce<<<768, 256, 0, stream>>>(pxconv, xconv);
    inproj_kernel<<<dim3(16, 8, 2), 256, 0, stream>>>(xconv, ipwT, xp, zpb, xpT);
    xdbl_gemm<<<dim3(32, 8), 256, 0, stream>>>(xpT, xwT, pxd);
    xdbl_reduce<<<1216, 256, 0, stream>>>(pxd, dt6R, BstT, CstT);
    delta_kernel<<<8192, 192, 0, stream>>>(dt6R, dtw, dtb, deltab);
    scan_part1<<<dim3(NCH, 2), 192, 0, stream>>>(xp, ord, deltab, BstT,
                                                 A_log, dirB, hend, Pend);
    scan_mid<<<384, 64, 0, stream>>>(hend, Pend);
    scan_part2<<<dim3(NCH, 2), 192, 0, stream>>>(xp, ord, deltab, BstT, CstT,
                                                 A_log, Dp, dirB, hend, ydir);
    cluster_kernel<<<128, 256, 0, stream>>>(xconv, fwp, fbp, vwp, vbp, pwp, pbp,
                                            alphap, betap, c96T);
    clproj_kernel<<<dim3(16, 8, 2), 256, 0, stream>>>(c96T, clwT, clb, cl);
    final_kernel<<<2048, 256, 0, stream>>>(ydir, zpb, cl, bc, lnw, lnb, woutT, out);
}